// Round 3
// baseline (1193.386 us; speedup 1.0000x reference)
//
#include <hip/hip_runtime.h>
#include <math.h>

#define NN 100000
#define NE 3200000
#define FIN 128
#define HD 64
#define TOUT 16
#define NB_SCAN ((NN + 255) / 256)   // 391
#define BSH 6                        // 64 nodes per bucket
#define NBK ((NN + 63) / 64)         // 1563 buckets

// ---------------- degree ----------------
__global__ __launch_bounds__(256) void k_deg(const int* __restrict__ dst, unsigned* __restrict__ deg) {
  int e = blockIdx.x * 256 + threadIdx.x;
  if (e < NE) atomicAdd(&deg[dst[e]], 1u);
}

__global__ __launch_bounds__(256) void k_dinv(const unsigned* __restrict__ deg, float* __restrict__ dinv) {
  int i = blockIdx.x * 256 + threadIdx.x;
  if (i < NN) dinv[i] = 1.0f / sqrtf((float)deg[i] + 1.0f);  // +1 self-loop
}

// ---------------- exclusive scan (3 phases) ----------------
__global__ __launch_bounds__(256) void k_scan_local(const unsigned* __restrict__ deg,
                                                    int* __restrict__ rowptr,
                                                    unsigned* __restrict__ blockSum) {
  __shared__ unsigned s[256];
  int t = threadIdx.x, i = blockIdx.x * 256 + t;
  unsigned v = (i < NN) ? deg[i] : 0u;
  s[t] = v;
  __syncthreads();
  for (int off = 1; off < 256; off <<= 1) {
    unsigned y = (t >= off) ? s[t - off] : 0u;
    __syncthreads();
    s[t] += y;
    __syncthreads();
  }
  if (i < NN) rowptr[i] = (int)(s[t] - v);          // local exclusive
  if (t == 255) blockSum[blockIdx.x] = s[255];
}

__global__ __launch_bounds__(512) void k_scan_block(unsigned* __restrict__ blockSum) {
  __shared__ unsigned s[512];
  int t = threadIdx.x;
  unsigned v = (t < NB_SCAN) ? blockSum[t] : 0u;
  s[t] = v;
  __syncthreads();
  for (int off = 1; off < 512; off <<= 1) {
    unsigned y = (t >= off) ? s[t - off] : 0u;
    __syncthreads();
    s[t] += y;
    __syncthreads();
  }
  if (t < NB_SCAN) blockSum[t] = s[t] - v;          // exclusive block offsets
}

__global__ __launch_bounds__(256) void k_scan_add(int* __restrict__ rowptr, const unsigned* __restrict__ blockSum,
                                                  int* __restrict__ bcur) {
  int i = blockIdx.x * 256 + threadIdx.x;
  if (i < NN) {
    int r = rowptr[i] + (int)blockSum[i >> 8];
    rowptr[i] = r;
    if ((i & 63) == 0) bcur[i >> BSH] = r;          // bucket cursor = rowptr at bucket start
  }
  if (i == 0) rowptr[NN] = NE;
}

// ---------------- phase A: partition edges into 64-node buckets ----------------
__global__ __launch_bounds__(256) void k_parta(const int* __restrict__ src, const int* __restrict__ dst,
                                               int* __restrict__ bcur, uint2* __restrict__ pairs) {
  int e = blockIdx.x * 256 + threadIdx.x;
  if (e >= NE) return;
  int s = src[e], d = dst[e];
  int p = atomicAdd(&bcur[d >> BSH], 1);
  pairs[p] = make_uint2((unsigned)s, (unsigned)d);
}

// ---------------- phase B: exact CSR within each bucket (LDS cursors) ----------------
__global__ __launch_bounds__(256) void k_csr(const uint2* __restrict__ pairs, const int* __restrict__ rowptr,
                                             int* __restrict__ csr_src) {
  __shared__ int cur[64];
  int b = blockIdx.x;
  int node0 = b << BSH;
  int node1 = node0 + 64; if (node1 > NN) node1 = NN;
  int t = threadIdx.x;
  if (t < 64) cur[t] = (node0 + t < NN) ? rowptr[node0 + t] : 0;
  __syncthreads();
  int beg = rowptr[node0], end = rowptr[node1];
  for (int i = beg + t; i < end; i += 256) {
    uint2 p = pairs[i];
    int pos = atomicAdd(&cur[p.y & 63], 1);
    csr_src[pos] = (int)p.x;
  }
}

// ---------------- tiled vector GEMM: C[n,M] = (A[n,K] @ W[K,M]) * (scale?scale[r]:1) ----------------
template<int K>
__global__ __launch_bounds__(256) void k_gemm(const float* __restrict__ A, const float* __restrict__ W,
                                              float* __restrict__ C, int n, int M,
                                              const float* __restrict__ scale) {
  constexpr int AS = K + 4;
  __shared__ float As[64 * AS];
  int tid = threadIdx.x;
  int rowBase = blockIdx.x * 64;
  int colBase = blockIdx.y * 64;
  int nrows = n - rowBase; if (nrows > 64) nrows = 64;

  for (int idx = tid * 4; idx < 64 * K; idx += 1024) {
    int row = idx / K;
    int k = idx - row * K;
    float4 v = make_float4(0.f, 0.f, 0.f, 0.f);
    if (row < nrows) v = *(const float4*)(A + (size_t)(rowBase + row) * K + k);
    *(float4*)(&As[row * AS + k]) = v;
  }
  __syncthreads();

  int tx = tid & 15, ty = tid >> 4;
  int c0 = colBase + tx * 4;
  int r0 = ty * 4;
  float acc[4][4] = {{0.f}};

  for (int k = 0; k < K; ++k) {
    float4 wv = *(const float4*)(W + (size_t)k * M + c0);
    float wa[4] = {wv.x, wv.y, wv.z, wv.w};
#pragma unroll
    for (int i = 0; i < 4; ++i) {
      float a = As[(r0 + i) * AS + k];
#pragma unroll
      for (int j = 0; j < 4; ++j) acc[i][j] = fmaf(a, wa[j], acc[i][j]);
    }
  }

#pragma unroll
  for (int i = 0; i < 4; ++i) {
    int r = rowBase + r0 + i;
    if (r < n) {
      float sc = scale ? scale[r] : 1.0f;
      float4 o = make_float4(acc[i][0] * sc, acc[i][1] * sc, acc[i][2] * sc, acc[i][3] * sc);
      *(float4*)(C + (size_t)r * M + c0) = o;
    }
  }
}

// ---------------- gather aggregation: h[d] = relu(dinv[d]*(hws[d] + sum_e hws[src_e]) + b) ----------------
__global__ __launch_bounds__(256) void k_gather(const float* __restrict__ hws, const int* __restrict__ rowptr,
                                                const int* __restrict__ csr_src, const float* __restrict__ dinv,
                                                const float* __restrict__ b, float* __restrict__ h) {
  int node = blockIdx.x * 4 + (threadIdx.x >> 6);
  if (node >= NN) return;
  int lane = threadIdx.x & 63;
  int beg = rowptr[node], end = rowptr[node + 1];
  float acc = hws[(size_t)node * HD + lane];       // self-loop (already dinv[node]-scaled)
  for (int base = beg; base < end; base += 64) {
    int rem = end - base;
    int m = rem < 64 ? rem : 64;
    int myS = (lane < m) ? csr_src[base + lane] : 0;
    int i = 0;
    for (; i + 4 <= m; i += 4) {
      int s0 = __shfl(myS, i), s1 = __shfl(myS, i + 1), s2 = __shfl(myS, i + 2), s3 = __shfl(myS, i + 3);
      float v0 = hws[(size_t)s0 * HD + lane];
      float v1 = hws[(size_t)s1 * HD + lane];
      float v2 = hws[(size_t)s2 * HD + lane];
      float v3 = hws[(size_t)s3 * HD + lane];
      acc += (v0 + v1) + (v2 + v3);
    }
    for (; i < m; ++i) {
      int s = __shfl(myS, i);
      acc += hws[(size_t)s * HD + lane];
    }
  }
  h[(size_t)node * HD + lane] = fmaxf(fmaf(dinv[node], acc, b[lane]), 0.f);
}

// ---------------- transpose GRU weights ----------------
__global__ __launch_bounds__(256) void k_transpose(const float* __restrict__ w_ih, const float* __restrict__ w_hh,
                                                   float* __restrict__ WtIH, float* __restrict__ WtHH) {
  int t = blockIdx.x * 256 + threadIdx.x;
  if (t < 192 * 64) {
    int j = t >> 6, k = t & 63;
    WtIH[k * 192 + j] = w_ih[t];
    WtHH[k * 192 + j] = w_hh[t];
  }
}

// ---------------- GRU elementwise ----------------
__global__ __launch_bounds__(256) void k_gru(const float* __restrict__ GI, const float* __restrict__ GH,
                                             const float* __restrict__ bih, const float* __restrict__ bhh,
                                             const float* __restrict__ prev, float* __restrict__ hnew,
                                             int start, int cnt) {
  int t = blockIdx.x * 256 + threadIdx.x;
  if (t >= cnt * HD) return;
  int j = t & 63, il = t >> 6;
  int gb = il * 192 + j;
  float rg = GI[gb] + bih[j] + GH[gb] + bhh[j];
  rg = 1.f / (1.f + expf(-rg));
  float zg = GI[gb + 64] + bih[64 + j] + GH[gb + 64] + bhh[64 + j];
  zg = 1.f / (1.f + expf(-zg));
  float nc = tanhf(GI[gb + 128] + bih[128 + j] + rg * (GH[gb + 128] + bhh[128 + j]));
  float h0 = prev[(size_t)(start + il) * HD + j];
  hnew[(size_t)(start + il) * HD + j] = (1.f - zg) * nc + zg * h0;
}

// ---------------- readout ----------------
__global__ __launch_bounds__(256) void k_readout(const float* __restrict__ hnew, const float* __restrict__ Wp,
                                                 const float* __restrict__ bp, float* __restrict__ out) {
  int t = blockIdx.x * 256 + threadIdx.x;
  if (t >= NN * TOUT) return;
  int col = t & 15;
  int i = t >> 4;
  const float* hr = hnew + (size_t)i * HD;
  float acc = bp[col];
#pragma unroll
  for (int k = 0; k < HD; ++k) acc = fmaf(hr[k], Wp[k * TOUT + col], acc);
  out[t] = acc;
}

extern "C" void kernel_launch(void* const* d_in, const int* in_sizes, int n_in,
                              void* d_out, int out_size, void* d_ws, size_t ws_size,
                              hipStream_t stream) {
  const float* x    = (const float*)d_in[0];
  const int*   ei   = (const int*)d_in[1];
  const float* prev = (const float*)d_in[2];
  const float* W1   = (const float*)d_in[3];
  const float* b1   = (const float*)d_in[4];
  const float* W2   = (const float*)d_in[5];
  const float* b2   = (const float*)d_in[6];
  const float* w_ih = (const float*)d_in[7];
  const float* w_hh = (const float*)d_in[8];
  const float* b_ih = (const float*)d_in[9];
  const float* b_hh = (const float*)d_in[10];
  const float* Wp   = (const float*)d_in[11];
  const float* bp   = (const float*)d_in[12];

  float* out  = (float*)d_out;                 // [NN,16]
  float* hnew = out + (size_t)NN * TOUT;       // [NN,64]

  char* ws = (char*)d_ws;
  float*    dinv    = (float*)(ws + 0);                    // 400,000
  unsigned* degI    = (unsigned*)(ws + 400000);            // 400,000
  int*      rowptr  = (int*)(ws + 800000);                 // 400,064 (NN+1)
  int*      bcur    = (int*)(ws + 1200064);                // 6,252 (NBK)
  unsigned* blkSum  = (unsigned*)(ws + 1208064);           // 4,160
  int*      csr_src = (int*)(ws + 1212224);                // 12,800,000
  float*    bufA    = (float*)(ws + 14012224);             // 25,600,000
  float*    bufB    = (float*)(ws + 39612224);             // 25,600,000 (aliased as pairBuf during CSR build)
  float*    bufC    = (float*)(ws + 65212224);             // 25,600,000
  float*    WtIH    = (float*)(ws + 90812224);             // 49,152
  float*    WtHH    = (float*)(ws + 90861376);             // 49,152
  uint2*    pairs   = (uint2*)bufB;                        // NE * 8B = 25,600,000

  const int* srcA = ei;
  const int* dstA = ei + NE;

  // ---- degree / norm / CSR build ----
  hipMemsetAsync(degI, 0, NN * sizeof(unsigned), stream);
  k_deg<<<(NE + 255) / 256, 256, 0, stream>>>(dstA, degI);
  k_dinv<<<(NN + 255) / 256, 256, 0, stream>>>(degI, dinv);
  k_scan_local<<<NB_SCAN, 256, 0, stream>>>(degI, rowptr, blkSum);
  k_scan_block<<<1, 512, 0, stream>>>(blkSum);
  k_scan_add<<<NB_SCAN, 256, 0, stream>>>(rowptr, blkSum, bcur);
  k_parta<<<(NE + 255) / 256, 256, 0, stream>>>(srcA, dstA, bcur, pairs);
  k_csr<<<NBK, 256, 0, stream>>>(pairs, rowptr, csr_src);

  // ---- GCN layer 1 ----
  k_gemm<FIN><<<dim3((NN + 63) / 64, 1), 256, 0, stream>>>(x, W1, bufA, NN, HD, dinv);
  k_gather<<<(NN + 3) / 4, 256, 0, stream>>>(bufA, rowptr, csr_src, dinv, b1, bufC);

  // ---- GCN layer 2 ----
  k_gemm<HD><<<dim3((NN + 63) / 64, 1), 256, 0, stream>>>(bufC, W2, bufA, NN, HD, dinv);
  k_gather<<<(NN + 3) / 4, 256, 0, stream>>>(bufA, rowptr, csr_src, dinv, b2, bufC);

  // ---- GRU (chunked) ----
  k_transpose<<<(192 * 64 + 255) / 256, 256, 0, stream>>>(w_ih, w_hh, WtIH, WtHH);
  const int CH = 25000;
  for (int c = 0; c < 4; ++c) {
    int start = c * CH;
    dim3 g((CH + 63) / 64, 3);
    k_gemm<HD><<<g, 256, 0, stream>>>(bufC + (size_t)start * HD, WtIH, bufA, CH, 192, nullptr);
    k_gemm<HD><<<g, 256, 0, stream>>>(prev + (size_t)start * HD, WtHH, bufB, CH, 192, nullptr);
    k_gru<<<(CH * HD + 255) / 256, 256, 0, stream>>>(bufA, bufB, b_ih, b_hh, prev, hnew, start, CH);
  }

  // ---- readout ----
  k_readout<<<(NN * TOUT + 255) / 256, 256, 0, stream>>>(hnew, Wp, bp, out);
}

// Round 4
// 761.269 us; speedup vs baseline: 1.5676x; 1.5676x over previous
//
#include <hip/hip_runtime.h>
#include <math.h>

#define NN 100000
#define NE 3200000
#define FIN 128
#define HD 64
#define TOUT 16
#define NB_SCAN ((NN + 255) / 256)   // 391
#define BSH 8                        // 256 nodes per bucket
#define NBUK ((NN + 255) / 256)      // 391 buckets
#define EPB 8192                     // edges per P1 block

// ---------------- degree ----------------
__global__ __launch_bounds__(256) void k_deg(const int* __restrict__ dst, unsigned* __restrict__ deg) {
  int e = blockIdx.x * 256 + threadIdx.x;
  if (e < NE) atomicAdd(&deg[dst[e]], 1u);
}

__global__ __launch_bounds__(256) void k_dinv(const unsigned* __restrict__ deg, float* __restrict__ dinv) {
  int i = blockIdx.x * 256 + threadIdx.x;
  if (i < NN) dinv[i] = 1.0f / sqrtf((float)deg[i] + 1.0f);  // +1 self-loop
}

// ---------------- exclusive scan (3 phases) ----------------
__global__ __launch_bounds__(256) void k_scan_local(const unsigned* __restrict__ deg,
                                                    int* __restrict__ rowptr,
                                                    unsigned* __restrict__ blockSum) {
  __shared__ unsigned s[256];
  int t = threadIdx.x, i = blockIdx.x * 256 + t;
  unsigned v = (i < NN) ? deg[i] : 0u;
  s[t] = v;
  __syncthreads();
  for (int off = 1; off < 256; off <<= 1) {
    unsigned y = (t >= off) ? s[t - off] : 0u;
    __syncthreads();
    s[t] += y;
    __syncthreads();
  }
  if (i < NN) rowptr[i] = (int)(s[t] - v);
  if (t == 255) blockSum[blockIdx.x] = s[255];
}

__global__ __launch_bounds__(512) void k_scan_block(unsigned* __restrict__ blockSum) {
  __shared__ unsigned s[512];
  int t = threadIdx.x;
  unsigned v = (t < NB_SCAN) ? blockSum[t] : 0u;
  s[t] = v;
  __syncthreads();
  for (int off = 1; off < 512; off <<= 1) {
    unsigned y = (t >= off) ? s[t - off] : 0u;
    __syncthreads();
    s[t] += y;
    __syncthreads();
  }
  if (t < NB_SCAN) blockSum[t] = s[t] - v;
}

__global__ __launch_bounds__(256) void k_scan_add(int* __restrict__ rowptr, const unsigned* __restrict__ blockSum,
                                                  int* __restrict__ bcur) {
  int i = blockIdx.x * 256 + threadIdx.x;
  if (i < NN) {
    int r = rowptr[i] + (int)blockSum[i >> 8];
    rowptr[i] = r;
    if ((i & 255) == 0) bcur[i >> BSH] = r;      // bucket cursor = rowptr at bucket start
  }
  if (i == 0) rowptr[NN] = NE;
}

// ---------------- P1: block-local histogram + contiguous run reservation ----------------
// Each block owns EPB contiguous edges; reserves one run per touched bucket; writes
// packed (dstLocal<<17 | src) into its runs (single-XCD full-line writebacks).
__global__ __launch_bounds__(256) void k_p1(const int* __restrict__ src, const int* __restrict__ dst,
                                            int* __restrict__ bcur, unsigned* __restrict__ packed) {
  __shared__ int hist[NBUK];
  __shared__ int base[NBUK];
  int t = threadIdx.x;
  int e0 = blockIdx.x * EPB;
  int e1 = e0 + EPB; if (e1 > NE) e1 = NE;

  for (int i = t; i < NBUK; i += 256) hist[i] = 0;
  __syncthreads();
  for (int e = e0 + t; e < e1; e += 256) atomicAdd(&hist[dst[e] >> BSH], 1);
  __syncthreads();
  for (int i = t; i < NBUK; i += 256) {
    int c = hist[i];
    base[i] = c ? atomicAdd(&bcur[i], c) : 0;
    hist[i] = 0;
  }
  __syncthreads();
  for (int e = e0 + t; e < e1; e += 256) {
    int d = dst[e];
    int b = d >> BSH;
    int p = base[b] + atomicAdd(&hist[b], 1);
    packed[p] = ((unsigned)(d & 255) << 17) | (unsigned)src[e];
  }
}

// ---------------- P2: node-exact CSR within each bucket (LDS node cursors) ----------------
__global__ __launch_bounds__(256) void k_p2(const unsigned* __restrict__ packed, const int* __restrict__ rowptr,
                                            int* __restrict__ csr_src) {
  __shared__ int cur[256];
  int b = blockIdx.x;
  int node0 = b << BSH;
  int node1 = node0 + 256; if (node1 > NN) node1 = NN;
  int t = threadIdx.x;
  cur[t] = (node0 + t < NN) ? rowptr[node0 + t] : 0;
  __syncthreads();
  int beg = rowptr[node0], end = rowptr[node1];
  for (int i = beg + t; i < end; i += 256) {
    unsigned v = packed[i];
    int pos = atomicAdd(&cur[v >> 17], 1);
    csr_src[pos] = (int)(v & 0x1FFFFu);
  }
}

// ---------------- tiled vector GEMM: C[n,M] = (A[n,K] @ W[K,M]) * (scale?scale[r]:1) ----------------
template<int K>
__global__ __launch_bounds__(256) void k_gemm(const float* __restrict__ A, const float* __restrict__ W,
                                              float* __restrict__ C, int n, int M,
                                              const float* __restrict__ scale) {
  constexpr int AS = K + 4;
  __shared__ float As[64 * AS];
  int tid = threadIdx.x;
  int rowBase = blockIdx.x * 64;
  int colBase = blockIdx.y * 64;
  int nrows = n - rowBase; if (nrows > 64) nrows = 64;

  for (int idx = tid * 4; idx < 64 * K; idx += 1024) {
    int row = idx / K;
    int k = idx - row * K;
    float4 v = make_float4(0.f, 0.f, 0.f, 0.f);
    if (row < nrows) v = *(const float4*)(A + (size_t)(rowBase + row) * K + k);
    *(float4*)(&As[row * AS + k]) = v;
  }
  __syncthreads();

  int tx = tid & 15, ty = tid >> 4;
  int c0 = colBase + tx * 4;
  int r0 = ty * 4;
  float acc[4][4] = {{0.f}};

  for (int k = 0; k < K; ++k) {
    float4 wv = *(const float4*)(W + (size_t)k * M + c0);
    float wa[4] = {wv.x, wv.y, wv.z, wv.w};
#pragma unroll
    for (int i = 0; i < 4; ++i) {
      float a = As[(r0 + i) * AS + k];
#pragma unroll
      for (int j = 0; j < 4; ++j) acc[i][j] = fmaf(a, wa[j], acc[i][j]);
    }
  }

#pragma unroll
  for (int i = 0; i < 4; ++i) {
    int r = rowBase + r0 + i;
    if (r < n) {
      float sc = scale ? scale[r] : 1.0f;
      float4 o = make_float4(acc[i][0] * sc, acc[i][1] * sc, acc[i][2] * sc, acc[i][3] * sc);
      *(float4*)(C + (size_t)r * M + c0) = o;
    }
  }
}

// ---------------- gather aggregation: h[d] = relu(dinv[d]*(hws[d] + sum_e hws[src_e]) + b) ----------------
__global__ __launch_bounds__(256) void k_gather(const float* __restrict__ hws, const int* __restrict__ rowptr,
                                                const int* __restrict__ csr_src, const float* __restrict__ dinv,
                                                const float* __restrict__ b, float* __restrict__ h) {
  int node = blockIdx.x * 4 + (threadIdx.x >> 6);
  if (node >= NN) return;
  int lane = threadIdx.x & 63;
  int beg = rowptr[node], end = rowptr[node + 1];
  float acc = hws[(size_t)node * HD + lane];       // self-loop (already dinv[node]-scaled)
  for (int base = beg; base < end; base += 64) {
    int rem = end - base;
    int m = rem < 64 ? rem : 64;
    int myS = (lane < m) ? csr_src[base + lane] : 0;
    int i = 0;
    for (; i + 4 <= m; i += 4) {
      int s0 = __shfl(myS, i), s1 = __shfl(myS, i + 1), s2 = __shfl(myS, i + 2), s3 = __shfl(myS, i + 3);
      float v0 = hws[(size_t)s0 * HD + lane];
      float v1 = hws[(size_t)s1 * HD + lane];
      float v2 = hws[(size_t)s2 * HD + lane];
      float v3 = hws[(size_t)s3 * HD + lane];
      acc += (v0 + v1) + (v2 + v3);
    }
    for (; i < m; ++i) {
      int s = __shfl(myS, i);
      acc += hws[(size_t)s * HD + lane];
    }
  }
  h[(size_t)node * HD + lane] = fmaxf(fmaf(dinv[node], acc, b[lane]), 0.f);
}

// ---------------- transpose GRU weights ----------------
__global__ __launch_bounds__(256) void k_transpose(const float* __restrict__ w_ih, const float* __restrict__ w_hh,
                                                   float* __restrict__ WtIH, float* __restrict__ WtHH) {
  int t = blockIdx.x * 256 + threadIdx.x;
  if (t < 192 * 64) {
    int j = t >> 6, k = t & 63;
    WtIH[k * 192 + j] = w_ih[t];
    WtHH[k * 192 + j] = w_hh[t];
  }
}

// ---------------- GRU elementwise ----------------
__global__ __launch_bounds__(256) void k_gru(const float* __restrict__ GI, const float* __restrict__ GH,
                                             const float* __restrict__ bih, const float* __restrict__ bhh,
                                             const float* __restrict__ prev, float* __restrict__ hnew,
                                             int start, int cnt) {
  int t = blockIdx.x * 256 + threadIdx.x;
  if (t >= cnt * HD) return;
  int j = t & 63, il = t >> 6;
  int gb = il * 192 + j;
  float rg = GI[gb] + bih[j] + GH[gb] + bhh[j];
  rg = 1.f / (1.f + expf(-rg));
  float zg = GI[gb + 64] + bih[64 + j] + GH[gb + 64] + bhh[64 + j];
  zg = 1.f / (1.f + expf(-zg));
  float nc = tanhf(GI[gb + 128] + bih[128 + j] + rg * (GH[gb + 128] + bhh[128 + j]));
  float h0 = prev[(size_t)(start + il) * HD + j];
  hnew[(size_t)(start + il) * HD + j] = (1.f - zg) * nc + zg * h0;
}

// ---------------- readout ----------------
__global__ __launch_bounds__(256) void k_readout(const float* __restrict__ hnew, const float* __restrict__ Wp,
                                                 const float* __restrict__ bp, float* __restrict__ out) {
  int t = blockIdx.x * 256 + threadIdx.x;
  if (t >= NN * TOUT) return;
  int col = t & 15;
  int i = t >> 4;
  const float* hr = hnew + (size_t)i * HD;
  float acc = bp[col];
#pragma unroll
  for (int k = 0; k < HD; ++k) acc = fmaf(hr[k], Wp[k * TOUT + col], acc);
  out[t] = acc;
}

extern "C" void kernel_launch(void* const* d_in, const int* in_sizes, int n_in,
                              void* d_out, int out_size, void* d_ws, size_t ws_size,
                              hipStream_t stream) {
  const float* x    = (const float*)d_in[0];
  const int*   ei   = (const int*)d_in[1];
  const float* prev = (const float*)d_in[2];
  const float* W1   = (const float*)d_in[3];
  const float* b1   = (const float*)d_in[4];
  const float* W2   = (const float*)d_in[5];
  const float* b2   = (const float*)d_in[6];
  const float* w_ih = (const float*)d_in[7];
  const float* w_hh = (const float*)d_in[8];
  const float* b_ih = (const float*)d_in[9];
  const float* b_hh = (const float*)d_in[10];
  const float* Wp   = (const float*)d_in[11];
  const float* bp   = (const float*)d_in[12];

  float* out  = (float*)d_out;                 // [NN,16]
  float* hnew = out + (size_t)NN * TOUT;       // [NN,64]

  char* ws = (char*)d_ws;
  float*    dinv    = (float*)(ws + 0);                    // 400,000
  unsigned* degI    = (unsigned*)(ws + 400000);            // 400,000
  int*      rowptr  = (int*)(ws + 800000);                 // 400,064 (NN+1)
  int*      bcur    = (int*)(ws + 1200064);                // 1,564 (NBUK)
  unsigned* blkSum  = (unsigned*)(ws + 1208064);           // 4,160
  int*      csr_src = (int*)(ws + 1212224);                // 12,800,000
  float*    bufA    = (float*)(ws + 14012224);             // 25,600,000
  float*    bufB    = (float*)(ws + 39612224);             // 25,600,000 (aliased: packed u32 during CSR build)
  float*    bufC    = (float*)(ws + 65212224);             // 25,600,000
  float*    WtIH    = (float*)(ws + 90812224);             // 49,152
  float*    WtHH    = (float*)(ws + 90861376);             // 49,152
  unsigned* packed  = (unsigned*)bufB;                     // NE * 4B

  const int* srcA = ei;
  const int* dstA = ei + NE;

  // ---- degree / norm / CSR build ----
  hipMemsetAsync(degI, 0, NN * sizeof(unsigned), stream);
  k_deg<<<(NE + 255) / 256, 256, 0, stream>>>(dstA, degI);
  k_dinv<<<(NN + 255) / 256, 256, 0, stream>>>(degI, dinv);
  k_scan_local<<<NB_SCAN, 256, 0, stream>>>(degI, rowptr, blkSum);
  k_scan_block<<<1, 512, 0, stream>>>(blkSum);
  k_scan_add<<<NB_SCAN, 256, 0, stream>>>(rowptr, blkSum, bcur);
  k_p1<<<(NE + EPB - 1) / EPB, 256, 0, stream>>>(srcA, dstA, bcur, packed);
  k_p2<<<NBUK, 256, 0, stream>>>(packed, rowptr, csr_src);

  // ---- GCN layer 1 ----
  k_gemm<FIN><<<dim3((NN + 63) / 64, 1), 256, 0, stream>>>(x, W1, bufA, NN, HD, dinv);
  k_gather<<<(NN + 3) / 4, 256, 0, stream>>>(bufA, rowptr, csr_src, dinv, b1, bufC);

  // ---- GCN layer 2 ----
  k_gemm<HD><<<dim3((NN + 63) / 64, 1), 256, 0, stream>>>(bufC, W2, bufA, NN, HD, dinv);
  k_gather<<<(NN + 3) / 4, 256, 0, stream>>>(bufA, rowptr, csr_src, dinv, b2, bufC);

  // ---- GRU (chunked) ----
  k_transpose<<<(192 * 64 + 255) / 256, 256, 0, stream>>>(w_ih, w_hh, WtIH, WtHH);
  const int CH = 25000;
  for (int c = 0; c < 4; ++c) {
    int start = c * CH;
    dim3 g((CH + 63) / 64, 3);
    k_gemm<HD><<<g, 256, 0, stream>>>(bufC + (size_t)start * HD, WtIH, bufA, CH, 192, nullptr);
    k_gemm<HD><<<g, 256, 0, stream>>>(prev + (size_t)start * HD, WtHH, bufB, CH, 192, nullptr);
    k_gru<<<(CH * HD + 255) / 256, 256, 0, stream>>>(bufA, bufB, b_ih, b_hh, prev, hnew, start, CH);
  }

  // ---- readout ----
  k_readout<<<(NN * TOUT + 255) / 256, 256, 0, stream>>>(hnew, Wp, bp, out);
}

// Round 5
// 609.329 us; speedup vs baseline: 1.9585x; 1.2494x over previous
//
#include <hip/hip_runtime.h>
#include <hip/hip_fp16.h>
#include <math.h>

#define NN 100000
#define NE 3200000
#define FIN 128
#define HD 64
#define TOUT 16
#define NB_SCAN ((NN + 255) / 256)   // 391
#define BSH 8                        // 256 nodes per bucket
#define NBUK ((NN + 255) / 256)      // 391 buckets
#define EPB 8192                     // edges per P1 block

// ---------------- degree ----------------
__global__ __launch_bounds__(256) void k_deg(const int* __restrict__ dst, unsigned* __restrict__ deg) {
  int e = blockIdx.x * 256 + threadIdx.x;
  if (e < NE) atomicAdd(&deg[dst[e]], 1u);
}

__global__ __launch_bounds__(256) void k_dinv(const unsigned* __restrict__ deg, float* __restrict__ dinv) {
  int i = blockIdx.x * 256 + threadIdx.x;
  if (i < NN) dinv[i] = 1.0f / sqrtf((float)deg[i] + 1.0f);  // +1 self-loop
}

// ---------------- exclusive scan (3 phases) ----------------
__global__ __launch_bounds__(256) void k_scan_local(const unsigned* __restrict__ deg,
                                                    int* __restrict__ rowptr,
                                                    unsigned* __restrict__ blockSum) {
  __shared__ unsigned s[256];
  int t = threadIdx.x, i = blockIdx.x * 256 + t;
  unsigned v = (i < NN) ? deg[i] : 0u;
  s[t] = v;
  __syncthreads();
  for (int off = 1; off < 256; off <<= 1) {
    unsigned y = (t >= off) ? s[t - off] : 0u;
    __syncthreads();
    s[t] += y;
    __syncthreads();
  }
  if (i < NN) rowptr[i] = (int)(s[t] - v);
  if (t == 255) blockSum[blockIdx.x] = s[255];
}

__global__ __launch_bounds__(512) void k_scan_block(unsigned* __restrict__ blockSum) {
  __shared__ unsigned s[512];
  int t = threadIdx.x;
  unsigned v = (t < NB_SCAN) ? blockSum[t] : 0u;
  s[t] = v;
  __syncthreads();
  for (int off = 1; off < 512; off <<= 1) {
    unsigned y = (t >= off) ? s[t - off] : 0u;
    __syncthreads();
    s[t] += y;
    __syncthreads();
  }
  if (t < NB_SCAN) blockSum[t] = s[t] - v;
}

__global__ __launch_bounds__(256) void k_scan_add(int* __restrict__ rowptr, const unsigned* __restrict__ blockSum,
                                                  int* __restrict__ bcur) {
  int i = blockIdx.x * 256 + threadIdx.x;
  if (i < NN) {
    int r = rowptr[i] + (int)blockSum[i >> 8];
    rowptr[i] = r;
    if ((i & 255) == 0) bcur[i >> BSH] = r;
  }
  if (i == 0) rowptr[NN] = NE;
}

// ---------------- P1: block-local histogram + contiguous run reservation ----------------
__global__ __launch_bounds__(256) void k_p1(const int* __restrict__ src, const int* __restrict__ dst,
                                            int* __restrict__ bcur, unsigned* __restrict__ packed) {
  __shared__ int hist[NBUK];
  __shared__ int base[NBUK];
  int t = threadIdx.x;
  int e0 = blockIdx.x * EPB;
  int e1 = e0 + EPB; if (e1 > NE) e1 = NE;

  for (int i = t; i < NBUK; i += 256) hist[i] = 0;
  __syncthreads();
  for (int e = e0 + t; e < e1; e += 256) atomicAdd(&hist[dst[e] >> BSH], 1);
  __syncthreads();
  for (int i = t; i < NBUK; i += 256) {
    int c = hist[i];
    base[i] = c ? atomicAdd(&bcur[i], c) : 0;
    hist[i] = 0;
  }
  __syncthreads();
  for (int e = e0 + t; e < e1; e += 256) {
    int d = dst[e];
    int b = d >> BSH;
    int p = base[b] + atomicAdd(&hist[b], 1);
    packed[p] = ((unsigned)(d & 255) << 17) | (unsigned)src[e];
  }
}

// ---------------- P2: node-exact CSR within each bucket ----------------
__global__ __launch_bounds__(256) void k_p2(const unsigned* __restrict__ packed, const int* __restrict__ rowptr,
                                            int* __restrict__ csr_src) {
  __shared__ int cur[256];
  int b = blockIdx.x;
  int node0 = b << BSH;
  int node1 = node0 + 256; if (node1 > NN) node1 = NN;
  int t = threadIdx.x;
  cur[t] = (node0 + t < NN) ? rowptr[node0 + t] : 0;
  __syncthreads();
  int beg = rowptr[node0], end = rowptr[node1];
  for (int i = beg + t; i < end; i += 256) {
    unsigned v = packed[i];
    int pos = atomicAdd(&cur[v >> 17], 1);
    csr_src[pos] = (int)(v & 0x1FFFFu);
  }
}

// ---------------- tiled GEMM with fp16 scaled output: Ch[n,M] = half((A@W) * scale[r]) ----------------
template<int K>
__global__ __launch_bounds__(256) void k_gemmh(const float* __restrict__ A, const float* __restrict__ W,
                                               __half* __restrict__ Ch, int n, int M,
                                               const float* __restrict__ scale) {
  constexpr int AS = K + 4;
  __shared__ float As[64 * AS];
  int tid = threadIdx.x;
  int rowBase = blockIdx.x * 64;
  int colBase = blockIdx.y * 64;
  int nrows = n - rowBase; if (nrows > 64) nrows = 64;

  for (int idx = tid * 4; idx < 64 * K; idx += 1024) {
    int row = idx / K;
    int k = idx - row * K;
    float4 v = make_float4(0.f, 0.f, 0.f, 0.f);
    if (row < nrows) v = *(const float4*)(A + (size_t)(rowBase + row) * K + k);
    *(float4*)(&As[row * AS + k]) = v;
  }
  __syncthreads();

  int tx = tid & 15, ty = tid >> 4;
  int c0 = colBase + tx * 4;
  int r0 = ty * 4;
  float acc[4][4] = {{0.f}};

  for (int k = 0; k < K; ++k) {
    float4 wv = *(const float4*)(W + (size_t)k * M + c0);
    float wa[4] = {wv.x, wv.y, wv.z, wv.w};
#pragma unroll
    for (int i = 0; i < 4; ++i) {
      float a = As[(r0 + i) * AS + k];
#pragma unroll
      for (int j = 0; j < 4; ++j) acc[i][j] = fmaf(a, wa[j], acc[i][j]);
    }
  }

#pragma unroll
  for (int i = 0; i < 4; ++i) {
    int r = rowBase + r0 + i;
    if (r < n) {
      float sc = scale[r];
      __half2 p0 = __floats2half2_rn(acc[i][0] * sc, acc[i][1] * sc);
      __half2 p1 = __floats2half2_rn(acc[i][2] * sc, acc[i][3] * sc);
      __half2* cp = (__half2*)(Ch + (size_t)r * M + c0);
      cp[0] = p0;
      cp[1] = p1;
    }
  }
}

// ---------------- gather (fp16 table): h[d] = relu(dinv[d]*(hws[d] + sum_e hws[src_e]) + b) ----------------
__global__ __launch_bounds__(256) void k_gather(const __half* __restrict__ hws, const int* __restrict__ rowptr,
                                                const int* __restrict__ csr_src, const float* __restrict__ dinv,
                                                const float* __restrict__ b, float* __restrict__ h) {
  int node = blockIdx.x * 4 + (threadIdx.x >> 6);
  if (node >= NN) return;
  int lane = threadIdx.x & 63;
  int beg = rowptr[node], end = rowptr[node + 1];
  float acc = __half2float(hws[(size_t)node * HD + lane]);   // self-loop (already dinv-scaled)
  for (int base = beg; base < end; base += 64) {
    int rem = end - base;
    int m = rem < 64 ? rem : 64;
    int myS = (lane < m) ? csr_src[base + lane] : 0;
    int i = 0;
    for (; i + 4 <= m; i += 4) {
      int s0 = __shfl(myS, i), s1 = __shfl(myS, i + 1), s2 = __shfl(myS, i + 2), s3 = __shfl(myS, i + 3);
      float v0 = __half2float(hws[(size_t)s0 * HD + lane]);
      float v1 = __half2float(hws[(size_t)s1 * HD + lane]);
      float v2 = __half2float(hws[(size_t)s2 * HD + lane]);
      float v3 = __half2float(hws[(size_t)s3 * HD + lane]);
      acc += (v0 + v1) + (v2 + v3);
    }
    for (; i < m; ++i) {
      int s = __shfl(myS, i);
      acc += __half2float(hws[(size_t)s * HD + lane]);
    }
  }
  h[(size_t)node * HD + lane] = fmaxf(fmaf(dinv[node], acc, b[lane]), 0.f);
}

// ---------------- transpose GRU weights: Wt[k][192] ----------------
__global__ __launch_bounds__(256) void k_transpose(const float* __restrict__ w_ih, const float* __restrict__ w_hh,
                                                   float* __restrict__ WtIH, float* __restrict__ WtHH) {
  int t = blockIdx.x * 256 + threadIdx.x;
  if (t < 192 * 64) {
    int j = t >> 6, k = t & 63;
    WtIH[k * 192 + j] = w_ih[t];
    WtHH[k * 192 + j] = w_hh[t];
  }
}

// ---------------- fused GRU: block = 64 nodes; r,z kept in registers across gate passes ----------------
__global__ __launch_bounds__(256) void k_grufused(const float* __restrict__ h, const float* __restrict__ prev,
                                                  const float* __restrict__ WtIH, const float* __restrict__ WtHH,
                                                  const float* __restrict__ bih, const float* __restrict__ bhh,
                                                  float* __restrict__ hnew) {
  __shared__ float hs[64 * 65];
  __shared__ float h0s[64 * 65];
  int tid = threadIdx.x;
  int rowBase = blockIdx.x * 64;
  int nrows = NN - rowBase; if (nrows > 64) nrows = 64;

  for (int idx = tid * 4; idx < 64 * 64; idx += 1024) {
    int r = idx >> 6, k = idx & 63;
    float4 v = make_float4(0.f, 0.f, 0.f, 0.f);
    float4 w = make_float4(0.f, 0.f, 0.f, 0.f);
    if (r < nrows) {
      v = *(const float4*)(h + (size_t)(rowBase + r) * HD + k);
      w = *(const float4*)(prev + (size_t)(rowBase + r) * HD + k);
    }
    hs[r * 65 + k] = v.x; hs[r * 65 + k + 1] = v.y; hs[r * 65 + k + 2] = v.z; hs[r * 65 + k + 3] = v.w;
    h0s[r * 65 + k] = w.x; h0s[r * 65 + k + 1] = w.y; h0s[r * 65 + k + 2] = w.z; h0s[r * 65 + k + 3] = w.w;
  }
  __syncthreads();

  int tx = tid & 15, ty = tid >> 4;
  int c0 = tx * 4;       // feature col within gate
  int r0 = ty * 4;       // node row within tile
  float rr[4][4], zz[4][4];

#pragma unroll
  for (int g = 0; g < 3; ++g) {
    float gi[4][4] = {{0.f}}, gh[4][4] = {{0.f}};
    for (int k = 0; k < HD; ++k) {
      float4 wi = *(const float4*)(WtIH + k * 192 + g * 64 + c0);
      float4 wh = *(const float4*)(WtHH + k * 192 + g * 64 + c0);
      float wia[4] = {wi.x, wi.y, wi.z, wi.w};
      float wha[4] = {wh.x, wh.y, wh.z, wh.w};
#pragma unroll
      for (int i = 0; i < 4; ++i) {
        float a = hs[(r0 + i) * 65 + k];
        float b0 = h0s[(r0 + i) * 65 + k];
#pragma unroll
        for (int j = 0; j < 4; ++j) {
          gi[i][j] = fmaf(a, wia[j], gi[i][j]);
          gh[i][j] = fmaf(b0, wha[j], gh[i][j]);
        }
      }
    }
    float4 biv = *(const float4*)(bih + g * 64 + c0);
    float4 bhv = *(const float4*)(bhh + g * 64 + c0);
    float bia[4] = {biv.x, biv.y, biv.z, biv.w};
    float bha[4] = {bhv.x, bhv.y, bhv.z, bhv.w};
    if (g == 0) {
#pragma unroll
      for (int i = 0; i < 4; ++i)
#pragma unroll
        for (int j = 0; j < 4; ++j)
          rr[i][j] = 1.f / (1.f + expf(-(gi[i][j] + bia[j] + gh[i][j] + bha[j])));
    } else if (g == 1) {
#pragma unroll
      for (int i = 0; i < 4; ++i)
#pragma unroll
        for (int j = 0; j < 4; ++j)
          zz[i][j] = 1.f / (1.f + expf(-(gi[i][j] + bia[j] + gh[i][j] + bha[j])));
    } else {
#pragma unroll
      for (int i = 0; i < 4; ++i) {
        int r = rowBase + r0 + i;
        if (r < NN) {
          float o[4];
#pragma unroll
          for (int j = 0; j < 4; ++j) {
            float nc = tanhf(gi[i][j] + bia[j] + rr[i][j] * (gh[i][j] + bha[j]));
            float h0v = h0s[(r0 + i) * 65 + c0 + j];
            o[j] = (1.f - zz[i][j]) * nc + zz[i][j] * h0v;
          }
          *(float4*)(hnew + (size_t)r * HD + c0) = make_float4(o[0], o[1], o[2], o[3]);
        }
      }
    }
  }
}

// ---------------- readout ----------------
__global__ __launch_bounds__(256) void k_readout(const float* __restrict__ hnew, const float* __restrict__ Wp,
                                                 const float* __restrict__ bp, float* __restrict__ out) {
  int t = blockIdx.x * 256 + threadIdx.x;
  if (t >= NN * TOUT) return;
  int col = t & 15;
  int i = t >> 4;
  const float* hr = hnew + (size_t)i * HD;
  float acc = bp[col];
#pragma unroll
  for (int k = 0; k < HD; ++k) acc = fmaf(hr[k], Wp[k * TOUT + col], acc);
  out[t] = acc;
}

extern "C" void kernel_launch(void* const* d_in, const int* in_sizes, int n_in,
                              void* d_out, int out_size, void* d_ws, size_t ws_size,
                              hipStream_t stream) {
  const float* x    = (const float*)d_in[0];
  const int*   ei   = (const int*)d_in[1];
  const float* prev = (const float*)d_in[2];
  const float* W1   = (const float*)d_in[3];
  const float* b1   = (const float*)d_in[4];
  const float* W2   = (const float*)d_in[5];
  const float* b2   = (const float*)d_in[6];
  const float* w_ih = (const float*)d_in[7];
  const float* w_hh = (const float*)d_in[8];
  const float* b_ih = (const float*)d_in[9];
  const float* b_hh = (const float*)d_in[10];
  const float* Wp   = (const float*)d_in[11];
  const float* bp   = (const float*)d_in[12];

  float* out  = (float*)d_out;                 // [NN,16]
  float* hnew = out + (size_t)NN * TOUT;       // [NN,64]

  char* ws = (char*)d_ws;
  float*    dinv    = (float*)(ws + 0);                    // 400,000
  unsigned* degI    = (unsigned*)(ws + 400000);            // 400,000
  int*      rowptr  = (int*)(ws + 800000);                 // 400,064
  int*      bcur    = (int*)(ws + 1200064);                // 1,564
  unsigned* blkSum  = (unsigned*)(ws + 1208064);           // 4,160
  int*      csr_src = (int*)(ws + 1212224);                // 12,800,000
  __half*   hwsH    = (__half*)(ws + 14012224);            // NN*64*2 = 12,800,000
  float*    bufB    = (float*)(ws + 26812224);             // 25,600,000 (packed u32 alias)
  float*    bufC    = (float*)(ws + 52412224);             // 25,600,000
  float*    WtIH    = (float*)(ws + 78012224);             // 49,152
  float*    WtHH    = (float*)(ws + 78061376);             // 49,152
  unsigned* packed  = (unsigned*)bufB;

  const int* srcA = ei;
  const int* dstA = ei + NE;

  // ---- degree / norm / CSR build ----
  hipMemsetAsync(degI, 0, NN * sizeof(unsigned), stream);
  k_deg<<<(NE + 255) / 256, 256, 0, stream>>>(dstA, degI);
  k_dinv<<<(NN + 255) / 256, 256, 0, stream>>>(degI, dinv);
  k_scan_local<<<NB_SCAN, 256, 0, stream>>>(degI, rowptr, blkSum);
  k_scan_block<<<1, 512, 0, stream>>>(blkSum);
  k_scan_add<<<NB_SCAN, 256, 0, stream>>>(rowptr, blkSum, bcur);
  k_p1<<<(NE + EPB - 1) / EPB, 256, 0, stream>>>(srcA, dstA, bcur, packed);
  k_p2<<<NBUK, 256, 0, stream>>>(packed, rowptr, csr_src);

  // ---- GCN layer 1 ----
  k_gemmh<FIN><<<dim3((NN + 63) / 64, 1), 256, 0, stream>>>(x, W1, hwsH, NN, HD, dinv);
  k_gather<<<(NN + 3) / 4, 256, 0, stream>>>(hwsH, rowptr, csr_src, dinv, b1, bufC);

  // ---- GCN layer 2 ----
  k_gemmh<HD><<<dim3((NN + 63) / 64, 1), 256, 0, stream>>>(bufC, W2, hwsH, NN, HD, dinv);
  k_gather<<<(NN + 3) / 4, 256, 0, stream>>>(hwsH, rowptr, csr_src, dinv, b2, bufC);

  // ---- fused GRU ----
  k_transpose<<<(192 * 64 + 255) / 256, 256, 0, stream>>>(w_ih, w_hh, WtIH, WtHH);
  k_grufused<<<(NN + 63) / 64, 256, 0, stream>>>(bufC, prev, WtIH, WtHH, b_ih, b_hh, hnew);

  // ---- readout ----
  k_readout<<<(NN * TOUT + 255) / 256, 256, 0, stream>>>(hnew, Wp, bp, out);
}